// Round 18
// baseline (113.021 us; speedup 1.0000x reference)
//
#include <hip/hip_runtime.h>

#define NTOKEN 200000
#define NINP   64
#define NEDGE  2000000
#define NBL    12800
#define NBKT   512
#define NPB    391            // nodes per bucket
#define CHUNK  4096
#define NCHK   ((NEDGE + CHUNK - 1) / CHUNK)   // 489
#define LROW   (NBKT + 1)                      // 513 ints per chunk in loffT
#define CAPB   6144           // per-bucket capacity (mean 3906, ~36 sigma headroom)
#define NCONV  3125           // emb-convert blocks at 1024 thr (3125*1024*4 == NTOKEN*NINP)

typedef unsigned short ushortT;

#define B2F(h) __uint_as_float(((unsigned)(h)) << 16)
__device__ __forceinline__ ushortT f2b(float x) {
    unsigned u = __float_as_uint(x);
    return (ushortT)((u + 0x7FFFu + ((u >> 16) & 1u)) >> 16);   // RNE
}

// ---- inclusive scan over s[0..511]; safe for any blockDim >= 512 ----
__device__ __forceinline__ void scan512c(int* s) {
    int t = threadIdx.x;
    for (int d = 1; d < 512; d <<= 1) {
        int v = (t >= d && t < 512) ? s[t - d] : 0;
        __syncthreads();
        if (t < 512) s[t] += v;
        __syncthreads();
    }
}

// ---- K0: zero ncnt+mark+need2 (404,096 B as ints) ----
__global__ void k_zero(int* __restrict__ z) {
    int i = blockIdx.x * blockDim.x + threadIdx.x;
    if (i < 404096 / 4) z[i] = 0;
}

// ---- K1: blocks 0..49 mark queried nodes; blocks 50..66 fold W12/bb ----
__global__ void k_mark_w12(const int* __restrict__ inp, unsigned char* __restrict__ mark,
                           unsigned char* __restrict__ need2,
                           const float* __restrict__ W1, const float* __restrict__ W2,
                           const float* __restrict__ b1, float* __restrict__ W12,
                           float* __restrict__ bb) {
    if (blockIdx.x < 50) {
        int t = blockIdx.x * 256 + threadIdx.x;
        if (t < NBL) { int n = inp[t]; mark[n] = 1; need2[n] = 1; }
    } else {
        int id = (blockIdx.x - 50) * 256 + threadIdx.x;
        if (id < 64 * 64) {
            int i = id >> 6, j = id & 63;
            float acc = 0.f;
            for (int k = 0; k < 128; ++k) acc += W1[i * 128 + k] * W2[k * 64 + j];
            W12[id] = acc;
        } else if (id < 64 * 64 + 64) {
            int j = id - 64 * 64;
            float acc = 0.f;
            for (int k = 0; k < 128; ++k) acc += b1[k] * W2[k * 64 + j];
            bb[j] = acc;
        }
    }
}

// ---- K2 (1024 thr): blocks 0..NCHK-1 per-chunk LDS bucket sort, dst cached in LDS;
//      blocks NCHK.. : emb fp32->bf16 streaming convert (overlapped) ----
__global__ __launch_bounds__(1024) void k_bucket(
        const int* __restrict__ src, const int* __restrict__ dst,
        int* __restrict__ E, int* __restrict__ loffT,
        const unsigned char* __restrict__ mark, unsigned char* __restrict__ need2,
        const float* __restrict__ emb, ushortT* __restrict__ embH) {
    __shared__ int sv[CHUNK];
    __shared__ int sd[CHUNK];   // cached dst
    __shared__ int h[NBKT];
    __shared__ int loff[NBKT];
    __shared__ int cur[NBKT];
    int t = threadIdx.x;
    int c = blockIdx.x;
    if (c >= NCHK) {                        // convert block: pure streaming
        int id = (c - NCHK) * 1024 + t;     // NCONV*1024 == NTOKEN*NINP/4 exactly
        float4 v = ((const float4*)emb)[id];
        ushort4 hh;
        hh.x = f2b(v.x); hh.y = f2b(v.y); hh.z = f2b(v.z); hh.w = f2b(v.w);
        ((ushort4*)embH)[id] = hh;
        return;
    }
    int base = c * CHUNK;
    int cnt = NEDGE - base; if (cnt > CHUNK) cnt = CHUNK;

    if (t < NBKT) { h[t] = 0; cur[t] = 0; }
    __syncthreads();
    for (int j = t; j < cnt; j += 1024) {
        int d = dst[base + j];
        sd[j] = d;
        atomicAdd(&h[(unsigned)d / NPB], 1);
    }
    __syncthreads();
    if (t < NBKT) loff[t] = h[t];
    __syncthreads();
    scan512c(loff);                         // inclusive
    if (t < NBKT) {
        int excl = loff[t] - h[t];
        loffT[c * LROW + t] = excl;         // coalesced (chunk-major)
        loff[t] = excl;
    }
    if (t == 0) loffT[c * LROW + 512] = cnt;
    __syncthreads();
    for (int j = t; j < cnt; j += 1024) {
        unsigned d = (unsigned)sd[j];       // from LDS, no global re-read
        unsigned bk = d / NPB;
        int s = src[base + j];
        if (mark[d]) need2[s] = 1;          // layer-2 frontier expansion, fused
        int packed = (int)(((d - bk * NPB) << 18) | (unsigned)s);
        int pl = atomicAdd(&cur[bk], 1);
        sv[loff[bk] + pl] = packed;
    }
    __syncthreads();
    for (int j = t; j < cnt; j += 1024)
        E[base + j] = sv[j];                // fully coalesced, own chunk slot
}

// ---- K3 (1024 thr): per-bucket segment-gather + CSR + dinv/rows/nlist ----
__global__ __launch_bounds__(1024) void k_csr(
        const int* __restrict__ E, const int* __restrict__ loffT,
        const unsigned char* __restrict__ need2,
        int* __restrict__ csr, float* __restrict__ dinv,
        int2* __restrict__ rows, int* __restrict__ nlist, int* __restrict__ ncnt) {
    __shared__ int eL[CAPB];
    __shared__ int csrL[CAPB];
    __shared__ int cnt[NBKT];
    __shared__ int off[NBKT];
    __shared__ int cur[NBKT];
    __shared__ int sgS[NBKT];
    __shared__ int sgL[NBKT];
    __shared__ unsigned char n2[NPB];
    __shared__ int nl[NPB];
    __shared__ int lcnt, nbase;
    int t = threadIdx.x;
    int b = blockIdx.x;
    int nodes = NTOKEN - b * NPB; if (nodes > NPB) nodes = NPB;

    if (t < NBKT) cnt[t] = 0;
    if (t == 0) lcnt = 0;
    if (t < nodes) n2[t] = need2[b * NPB + t];
    if (t < NBKT) {
        int s = 0, l = 0;
        if (t < NCHK) {
            s = loffT[t * LROW + b];
            l = loffT[t * LROW + b + 1] - s;
            s += t * CHUNK;
        }
        sgS[t] = s; sgL[t] = l; off[t] = l;
    }
    __syncthreads();
    scan512c(off);                          // inclusive over segment lengths
    int n = off[NBKT - 1];
    {
        int seg = t >> 1, half = t & 1;     // two threads per chunk-segment
        if (seg < NCHK) {
            int o = off[seg] - sgL[seg];
            int s = sgS[seg];
            int l = sgL[seg];
            for (int k = half; k < l; k += 2)
                eL[o + k] = E[s + k];
        }
    }
    __syncthreads();
    for (int j = t; j < n; j += 1024)
        atomicAdd(&cnt[eL[j] >> 18], 1);
    __syncthreads();
    if (t < NBKT) off[t] = cnt[t];
    __syncthreads();
    scan512c(off);                          // inclusive per-node counts
    int cbase = b * CAPB;
    if (t < nodes) {
        int node = b * NPB + t;
        dinv[node] = rsqrtf((float)(cnt[t] + 1));
        rows[node] = make_int2(cbase + off[t] - cnt[t], cbase + off[t]);
        if (n2[t]) nl[atomicAdd(&lcnt, 1)] = node;
    }
    if (t < NBKT) cur[t] = off[t] - cnt[t];
    __syncthreads();
    if (t == 0) nbase = lcnt ? atomicAdd(ncnt, lcnt) : 0;
    __syncthreads();
    if (t < lcnt) nlist[nbase + t] = nl[t];
    for (int j = t; j < n; j += 1024) {     // selective placement: needed rows only
        int v = eL[j];
        int node = v >> 18;
        if (!n2[node]) continue;
        int pos = atomicAdd(&cur[node], 1);
        csrL[pos] = v & 0x3FFFF;
    }
    __syncthreads();
    for (int j = t; j < n; j += 1024)
        csr[cbase + j] = csrL[j];
}

// ---- single-node tail batch (deg>64, rare): groups of 8 edges ----
#define TAIL_GATHER(bN, dN, myEN, myWN, AX, AY, AZ, AW, WS)                         \
    for (int base = 64; base < dN; base += 64) {                                    \
        int mm = dN - base; if (mm > 64) mm = 64;                                   \
        int tE = 0; float tW = 0.f;                                                 \
        if (lane < mm) { tE = csr[bN + base + lane]; tW = dinv[tE]; }               \
        for (int e = 0; e < mm; e += 8) {                                           \
            int   sA = __shfl(tE, e + qe);     float wA = __shfl(tW, e + qe);       \
            int   sB = __shfl(tE, e + 4 + qe); float wB = __shfl(tW, e + 4 + qe);   \
            uint2 vA = *(const uint2*)(tab + sA * NINP + qf * 4);                   \
            uint2 vB = *(const uint2*)(tab + sB * NINP + qf * 4);                   \
            AX += wA * __uint_as_float(vA.x << 16) + wB * __uint_as_float(vB.x << 16);          \
            AY += wA * __uint_as_float(vA.x & 0xffff0000u) + wB * __uint_as_float(vB.x & 0xffff0000u); \
            AZ += wA * __uint_as_float(vA.y << 16) + wB * __uint_as_float(vB.y << 16);          \
            AW += wA * __uint_as_float(vA.y & 0xffff0000u) + wB * __uint_as_float(vB.y & 0xffff0000u); \
            WS += wA + wB;                                                          \
        }                                                                           \
    }

// ---- pair gather: two nodes' quad-row gathers interleaved (4 loads in flight) ----
__device__ __forceinline__ void pair_gather(const ushortT* __restrict__ tab,
                                            const int* __restrict__ csr,
                                            const float* __restrict__ dinv,
                                            int b0, int d0, int b1, int d1,
                                            int lane, int qe, int qf,
                                            int myE0, float myW0, int myE1, float myW1,
                                            float4* g0, float4* g1,
                                            float* sw0, float* sw1) {
    float x0 = 0.f, y0 = 0.f, z0 = 0.f, w0a = 0.f, ws0 = 0.f;
    float x1 = 0.f, y1 = 0.f, z1 = 0.f, w1a = 0.f, ws1 = 0.f;
    int m0 = d0 > 64 ? 64 : d0;
    int m1 = d1 > 64 ? 64 : d1;
    int mx = m0 > m1 ? m0 : m1;
    for (int e = 0; e < mx; e += 8) {
        int   sA0 = __shfl(myE0, e + qe);     float wA0 = __shfl(myW0, e + qe);
        int   sB0 = __shfl(myE0, e + 4 + qe); float wB0 = __shfl(myW0, e + 4 + qe);
        int   sA1 = __shfl(myE1, e + qe);     float wA1 = __shfl(myW1, e + qe);
        int   sB1 = __shfl(myE1, e + 4 + qe); float wB1 = __shfl(myW1, e + 4 + qe);
        uint2 vA0 = *(const uint2*)(tab + sA0 * NINP + qf * 4);
        uint2 vB0 = *(const uint2*)(tab + sB0 * NINP + qf * 4);
        uint2 vA1 = *(const uint2*)(tab + sA1 * NINP + qf * 4);
        uint2 vB1 = *(const uint2*)(tab + sB1 * NINP + qf * 4);
        x0  += wA0 * __uint_as_float(vA0.x << 16)         + wB0 * __uint_as_float(vB0.x << 16);
        y0  += wA0 * __uint_as_float(vA0.x & 0xffff0000u) + wB0 * __uint_as_float(vB0.x & 0xffff0000u);
        z0  += wA0 * __uint_as_float(vA0.y << 16)         + wB0 * __uint_as_float(vB0.y << 16);
        w0a += wA0 * __uint_as_float(vA0.y & 0xffff0000u) + wB0 * __uint_as_float(vB0.y & 0xffff0000u);
        ws0 += wA0 + wB0;
        x1  += wA1 * __uint_as_float(vA1.x << 16)         + wB1 * __uint_as_float(vB1.x << 16);
        y1  += wA1 * __uint_as_float(vA1.x & 0xffff0000u) + wB1 * __uint_as_float(vB1.x & 0xffff0000u);
        z1  += wA1 * __uint_as_float(vA1.y << 16)         + wB1 * __uint_as_float(vB1.y << 16);
        w1a += wA1 * __uint_as_float(vA1.y & 0xffff0000u) + wB1 * __uint_as_float(vB1.y & 0xffff0000u);
        ws1 += wA1 + wB1;
    }
    if (d0 > 64) { TAIL_GATHER(b0, d0, myE0, myW0, x0, y0, z0, w0a, ws0) }
    if (d1 > 64) { TAIL_GATHER(b1, d1, myE1, myW1, x1, y1, z1, w1a, ws1) }
    x0  += __shfl_xor(x0, 16);  x0  += __shfl_xor(x0, 32);
    y0  += __shfl_xor(y0, 16);  y0  += __shfl_xor(y0, 32);
    z0  += __shfl_xor(z0, 16);  z0  += __shfl_xor(z0, 32);
    w0a += __shfl_xor(w0a, 16); w0a += __shfl_xor(w0a, 32);
    ws0 += __shfl_xor(ws0, 16); ws0 += __shfl_xor(ws0, 32);
    x1  += __shfl_xor(x1, 16);  x1  += __shfl_xor(x1, 32);
    y1  += __shfl_xor(y1, 16);  y1  += __shfl_xor(y1, 32);
    z1  += __shfl_xor(z1, 16);  z1  += __shfl_xor(z1, 32);
    w1a += __shfl_xor(w1a, 16); w1a += __shfl_xor(w1a, 32);
    ws1 += __shfl_xor(ws1, 16); ws1 += __shfl_xor(ws1, 32);
    *g0 = make_float4(x0, y0, z0, w0a);
    *g1 = make_float4(x1, y1, z1, w1a);
    *sw0 = ws0; *sw1 = ws1;
}

// ---- K4: layer-1 gather, two nodes per wave iteration, interleaved pair gather ----
__global__ void k_gather1(const int* __restrict__ nlist, const int* __restrict__ ncnt,
                          const int2* __restrict__ rows, const int* __restrict__ csr,
                          const float* __restrict__ dinv, const ushortT* __restrict__ embH,
                          ushortT* __restrict__ P1H) {
    int lane = threadIdx.x & 63;
    int qe = lane >> 4, qf = lane & 15;
    int wid = blockIdx.x * (blockDim.x >> 6) + (threadIdx.x >> 6);
    int nw  = gridDim.x * (blockDim.x >> 6);
    int ncount = *ncnt;
    for (int p = wid; 2 * p < ncount; p += nw) {
        int i0 = nlist[2 * p];
        bool has1 = (2 * p + 1 < ncount);
        int i1 = has1 ? nlist[2 * p + 1] : i0;
        int2 r0 = rows[i0];
        int2 r1 = rows[i1];
        int b0 = r0.x, d0 = r0.y - r0.x;
        int b1 = r1.x, d1 = has1 ? (r1.y - r1.x) : 0;
        float di0 = rsqrtf((float)(d0 + 1));        // == dinv[i0], recomputed
        float di1 = rsqrtf((float)(d1 + 1));
        int m0 = d0 > 64 ? 64 : d0;
        int m1 = d1 > 64 ? 64 : d1;
        int e0 = 0; float w0 = 0.f;
        if (lane < m0) { e0 = csr[b0 + lane]; w0 = dinv[e0]; }
        int e1 = 0; float w1 = 0.f;
        if (lane < m1) { e1 = csr[b1 + lane]; w1 = dinv[e1]; }
        float4 g0, g1; float sw0, sw1;
        pair_gather(embH, csr, dinv, b0, d0, b1, d1, lane, qe, qf,
                    e0, w0, e1, w1, &g0, &g1, &sw0, &sw1);
        if (qe == 0) {
            uint2 sv0 = *(const uint2*)(embH + i0 * NINP + qf * 4);
            ushort4 o0;
            o0.x = f2b(di0 * (di0 * __uint_as_float(sv0.x << 16)         + g0.x));
            o0.y = f2b(di0 * (di0 * __uint_as_float(sv0.x & 0xffff0000u) + g0.y));
            o0.z = f2b(di0 * (di0 * __uint_as_float(sv0.y << 16)         + g0.z));
            o0.w = f2b(di0 * (di0 * __uint_as_float(sv0.y & 0xffff0000u) + g0.w));
            *(ushort4*)(P1H + i0 * NINP + qf * 4) = o0;
            if (has1) {
                uint2 sv1 = *(const uint2*)(embH + i1 * NINP + qf * 4);
                ushort4 o1;
                o1.x = f2b(di1 * (di1 * __uint_as_float(sv1.x << 16)         + g1.x));
                o1.y = f2b(di1 * (di1 * __uint_as_float(sv1.x & 0xffff0000u) + g1.y));
                o1.z = f2b(di1 * (di1 * __uint_as_float(sv1.y << 16)         + g1.z));
                o1.w = f2b(di1 * (di1 * __uint_as_float(sv1.y & 0xffff0000u) + g1.w));
                *(ushort4*)(P1H + i1 * NINP + qf * 4) = o1;
            }
        }
    }
}

// ---- K5: final layer-2 gather (pairing two tokens per wave) + 64x64 GEMM + biases ----
__global__ void k_final(const int* __restrict__ inp, const int2* __restrict__ rows,
                        const int* __restrict__ csr, const float* __restrict__ dinv,
                        const ushortT* __restrict__ P1H, const float* __restrict__ W12,
                        const float* __restrict__ bb, const float* __restrict__ b2,
                        float* __restrict__ out) {
    int t0 = (blockIdx.x * 4 + (threadIdx.x >> 6)) * 2;
    if (t0 >= NBL) return;
    int lane = threadIdx.x & 63;
    int qe = lane >> 4, qf = lane & 15;
    int n0 = inp[t0];
    int n1 = inp[t0 + 1];                   // NBL even -> always valid
    int2 r0 = rows[n0];
    int2 r1 = rows[n1];
    int b0 = r0.x, d0 = r0.y - r0.x;
    int b1 = r1.x, d1 = r1.y - r1.x;
    float dn0 = rsqrtf((float)(d0 + 1));
    float dn1 = rsqrtf((float)(d1 + 1));
    int m0 = d0 > 64 ? 64 : d0;
    int m1 = d1 > 64 ? 64 : d1;
    int e0 = 0; float w0 = 0.f;
    if (lane < m0) { e0 = csr[b0 + lane]; w0 = dinv[e0]; }
    int e1 = 0; float w1 = 0.f;
    if (lane < m1) { e1 = csr[b1 + lane]; w1 = dinv[e1]; }
    float4 g0, g1; float sw0, sw1;
    pair_gather(P1H, csr, dinv, b0, d0, b1, d1, lane, qe, qf,
                e0, w0, e1, w1, &g0, &g1, &sw0, &sw1);
    uint2 sv0 = *(const uint2*)(P1H + n0 * NINP + qf * 4);
    uint2 sv1 = *(const uint2*)(P1H + n1 * NINP + qf * 4);
    float4 p0, p1;
    p0.x = dn0 * (dn0 * __uint_as_float(sv0.x << 16)         + g0.x);
    p0.y = dn0 * (dn0 * __uint_as_float(sv0.x & 0xffff0000u) + g0.y);
    p0.z = dn0 * (dn0 * __uint_as_float(sv0.y << 16)         + g0.z);
    p0.w = dn0 * (dn0 * __uint_as_float(sv0.y & 0xffff0000u) + g0.w);
    p1.x = dn1 * (dn1 * __uint_as_float(sv1.x << 16)         + g1.x);
    p1.y = dn1 * (dn1 * __uint_as_float(sv1.x & 0xffff0000u) + g1.y);
    p1.z = dn1 * (dn1 * __uint_as_float(sv1.y << 16)         + g1.z);
    p1.w = dn1 * (dn1 * __uint_as_float(sv1.y & 0xffff0000u) + g1.w);
    float sS0 = dn0 + sw0;
    float sS1 = dn1 + sw1;
    float bbl = bb[lane], b2l = b2[lane];
    float acc0 = b2l + dn0 * sS0 * bbl;
    float acc1 = b2l + dn1 * sS1 * bbl;
#pragma unroll
    for (int q = 0; q < 16; ++q) {
        float w0c = W12[(4 * q + 0) * 64 + lane];
        float w1c = W12[(4 * q + 1) * 64 + lane];
        float w2c = W12[(4 * q + 2) * 64 + lane];
        float w3c = W12[(4 * q + 3) * 64 + lane];
        acc0 += __shfl(p0.x, q) * w0c + __shfl(p0.y, q) * w1c
              + __shfl(p0.z, q) * w2c + __shfl(p0.w, q) * w3c;
        acc1 += __shfl(p1.x, q) * w0c + __shfl(p1.y, q) * w1c
              + __shfl(p1.z, q) * w2c + __shfl(p1.w, q) * w3c;
    }
    out[t0 * 64 + lane] = acc0;
    out[(t0 + 1) * 64 + lane] = acc1;
}

extern "C" void kernel_launch(void* const* d_in, const int* in_sizes, int n_in,
                              void* d_out, int out_size, void* d_ws, size_t ws_size,
                              hipStream_t stream) {
    const int*   inp  = (const int*)d_in[0];
    const int*   eidx = (const int*)d_in[3];
    const int*   esrc = eidx;
    const int*   edst = eidx + NEDGE;
    const float* emb  = (const float*)d_in[4];
    const float* W1   = (const float*)d_in[5];
    const float* b1   = (const float*)d_in[6];
    const float* W2   = (const float*)d_in[7];
    const float* b2   = (const float*)d_in[8];
    float* out = (float*)d_out;

    char* ws = (char*)d_ws;
    int*           ncnt   = (int*)(ws + 0);            //         4
    unsigned char* mark   = (unsigned char*)(ws + 4096);      // 200,000
    unsigned char* need2  = (unsigned char*)(ws + 204096);    // 200,000
    int2*          rows   = (int2*)(ws + 404096);      //  1,600,000
    float*         dinv   = (float*)(ws + 2004096);    //    800,000
    int*           nlist  = (int*)(ws + 2804096);      //    800,000
    int*           csr    = (int*)(ws + 3604096);      // 12,582,912
    float*         W12    = (float*)(ws + 16187008);   //     16,384
    float*         bb     = (float*)(ws + 16203392);   //        256
    ushortT*       embH   = (ushortT*)(ws + 16203648); // 25,600,000
    ushortT*       P1H    = (ushortT*)(ws + 41803648); // 25,600,000 (end 67,403,648)
    // E + loffT alias the P1H region: both dead before P1H is first written
    int*           E      = (int*)(ws + 41803648);     //  8,011,776
    int*           loffT  = (int*)(ws + 49815424);     //  1,003,428

    const int B = 256;

    k_zero    <<<(404096 / 4 + B - 1) / B, B, 0, stream>>>((int*)ws);
    k_mark_w12<<<67, B, 0, stream>>>(inp, mark, need2, W1, W2, b1, W12, bb);
    k_bucket  <<<NCHK + NCONV, 1024, 0, stream>>>(esrc, edst, E, loffT, mark, need2, emb, embH);
    k_csr     <<<NBKT, 1024, 0, stream>>>(E, loffT, need2, csr, dinv, rows, nlist, ncnt);

    k_gather1 <<<2048, B, 0, stream>>>(nlist, ncnt, rows, csr, dinv, embH, P1H);
    k_final   <<<(NBL / 2 + 3) / 4, B, 0, stream>>>(inp, rows, csr, dinv, P1H, W12, bb, b2, out);
}

// Round 19
// 106.508 us; speedup vs baseline: 1.0612x; 1.0612x over previous
//
#include <hip/hip_runtime.h>

#define NTOKEN 200000
#define NINP   64
#define NEDGE  2000000
#define NBL    12800
#define NBKT   512
#define NPB    391            // nodes per bucket
#define CHUNK  4096
#define NCHK   ((NEDGE + CHUNK - 1) / CHUNK)   // 489
#define LROW   (NBKT + 1)                      // 513 ints per chunk in loffT
#define CAPB   6144           // per-bucket capacity (mean 3906, ~36 sigma headroom)
#define NCONV  6250           // emb-convert blocks at 512 thr (6250*512*4 == NTOKEN*NINP)

typedef unsigned short ushortT;

#define B2F(h) __uint_as_float(((unsigned)(h)) << 16)
__device__ __forceinline__ ushortT f2b(float x) {
    unsigned u = __float_as_uint(x);
    return (ushortT)((u + 0x7FFFu + ((u >> 16) & 1u)) >> 16);   // RNE
}

// ---- inclusive scan over s[0..511], 512 threads, caller syncs before ----
__device__ __forceinline__ void scan512b(int* s) {
    int t = threadIdx.x;
    for (int d = 1; d < 512; d <<= 1) {
        int v = (t >= d) ? s[t - d] : 0;
        __syncthreads();
        s[t] += v;
        __syncthreads();
    }
}

// ---- K0: zero ncnt+mark+need2 (404,096 B as ints) ----
__global__ void k_zero(int* __restrict__ z) {
    int i = blockIdx.x * blockDim.x + threadIdx.x;
    if (i < 404096 / 4) z[i] = 0;
}

// ---- K1: blocks 0..49 mark queried nodes; blocks 50..66 fold W12/bb ----
__global__ void k_mark_w12(const int* __restrict__ inp, unsigned char* __restrict__ mark,
                           unsigned char* __restrict__ need2,
                           const float* __restrict__ W1, const float* __restrict__ W2,
                           const float* __restrict__ b1, float* __restrict__ W12,
                           float* __restrict__ bb) {
    if (blockIdx.x < 50) {
        int t = blockIdx.x * 256 + threadIdx.x;
        if (t < NBL) { int n = inp[t]; mark[n] = 1; need2[n] = 1; }
    } else {
        int id = (blockIdx.x - 50) * 256 + threadIdx.x;
        if (id < 64 * 64) {
            int i = id >> 6, j = id & 63;
            float acc = 0.f;
            for (int k = 0; k < 128; ++k) acc += W1[i * 128 + k] * W2[k * 64 + j];
            W12[id] = acc;
        } else if (id < 64 * 64 + 64) {
            int j = id - 64 * 64;
            float acc = 0.f;
            for (int k = 0; k < 128; ++k) acc += b1[k] * W2[k * 64 + j];
            bb[j] = acc;
        }
    }
}

// ---- K2 (512 thr): blocks 0..NCHK-1 per-chunk LDS bucket sort, dst cached in LDS;
//      blocks NCHK.. : emb fp32->bf16 streaming convert (overlapped) ----
__global__ __launch_bounds__(512) void k_bucket(
        const int* __restrict__ src, const int* __restrict__ dst,
        int* __restrict__ E, int* __restrict__ loffT,
        const unsigned char* __restrict__ mark, unsigned char* __restrict__ need2,
        const float* __restrict__ emb, ushortT* __restrict__ embH) {
    __shared__ int sv[CHUNK];
    __shared__ int sd[CHUNK];   // cached dst
    __shared__ int h[NBKT];
    __shared__ int loff[NBKT];
    __shared__ int cur[NBKT];
    int t = threadIdx.x;
    int c = blockIdx.x;
    if (c >= NCHK) {                        // convert block: pure streaming
        int id = (c - NCHK) * 512 + t;      // NCONV*512 == NTOKEN*NINP/4 exactly
        float4 v = ((const float4*)emb)[id];
        ushort4 hh;
        hh.x = f2b(v.x); hh.y = f2b(v.y); hh.z = f2b(v.z); hh.w = f2b(v.w);
        ((ushort4*)embH)[id] = hh;
        return;
    }
    int base = c * CHUNK;
    int cnt = NEDGE - base; if (cnt > CHUNK) cnt = CHUNK;

    h[t] = 0; cur[t] = 0;
    __syncthreads();
    for (int j = t; j < cnt; j += 512) {
        int d = dst[base + j];
        sd[j] = d;
        atomicAdd(&h[(unsigned)d / NPB], 1);
    }
    __syncthreads();
    loff[t] = h[t];
    __syncthreads();
    scan512b(loff);                         // inclusive
    int excl = loff[t] - h[t];
    loffT[c * LROW + t] = excl;             // coalesced (chunk-major)
    if (t == 0) loffT[c * LROW + 512] = cnt;
    loff[t] = excl;
    __syncthreads();
    for (int j = t; j < cnt; j += 512) {
        unsigned d = (unsigned)sd[j];       // from LDS, no global re-read
        unsigned bk = d / NPB;
        int s = src[base + j];
        if (mark[d]) need2[s] = 1;          // layer-2 frontier expansion, fused
        int packed = (int)(((d - bk * NPB) << 18) | (unsigned)s);
        int pl = atomicAdd(&cur[bk], 1);
        sv[loff[bk] + pl] = packed;
    }
    __syncthreads();
    for (int j = t; j < cnt; j += 512)
        E[base + j] = sv[j];                // fully coalesced, own chunk slot
}

// ---- K3 (512 thr): per-bucket segment-gather + CSR + dinv/rows/nlist ----
__global__ __launch_bounds__(512) void k_csr(
        const int* __restrict__ E, const int* __restrict__ loffT,
        const unsigned char* __restrict__ need2,
        int* __restrict__ csr, float* __restrict__ dinv,
        int2* __restrict__ rows, int* __restrict__ nlist, int* __restrict__ ncnt) {
    __shared__ int eL[CAPB];
    __shared__ int csrL[CAPB];
    __shared__ int cnt[NBKT];
    __shared__ int off[NBKT];
    __shared__ int cur[NBKT];
    __shared__ int sgS[NBKT];
    __shared__ int sgL[NBKT];
    __shared__ unsigned char n2[NPB];
    __shared__ int nl[NPB];
    __shared__ int lcnt, nbase;
    int t = threadIdx.x;
    int b = blockIdx.x;
    int nodes = NTOKEN - b * NPB; if (nodes > NPB) nodes = NPB;

    cnt[t] = 0;
    if (t == 0) lcnt = 0;
    if (t < nodes) n2[t] = need2[b * NPB + t];
    {
        int s = 0, l = 0;
        if (t < NCHK) {
            s = loffT[t * LROW + b];
            l = loffT[t * LROW + b + 1] - s;
            s += t * CHUNK;
        }
        sgS[t] = s; sgL[t] = l; off[t] = l;
    }
    __syncthreads();
    scan512b(off);                          // inclusive over segment lengths
    int n = off[NBKT - 1];
    {
        int o = off[t] - sgL[t];
        int s = sgS[t];
        int l = sgL[t];
        for (int k = 0; k < l; ++k)
            eL[o + k] = E[s + k];           // one chunk-segment per thread
    }
    __syncthreads();
    for (int j = t; j < n; j += 512)
        atomicAdd(&cnt[eL[j] >> 18], 1);
    __syncthreads();
    off[t] = cnt[t];
    __syncthreads();
    scan512b(off);                          // inclusive per-node counts
    int cbase = b * CAPB;
    if (t < nodes) {
        int node = b * NPB + t;
        dinv[node] = rsqrtf((float)(cnt[t] + 1));
        rows[node] = make_int2(cbase + off[t] - cnt[t], cbase + off[t]);
        if (n2[t]) nl[atomicAdd(&lcnt, 1)] = node;
    }
    cur[t] = off[t] - cnt[t];
    __syncthreads();
    if (t == 0) nbase = lcnt ? atomicAdd(ncnt, lcnt) : 0;
    __syncthreads();
    if (t < lcnt) nlist[nbase + t] = nl[t];
    for (int j = t; j < n; j += 512) {      // selective placement: needed rows only
        int v = eL[j];
        int node = v >> 18;
        if (!n2[node]) continue;
        int pos = atomicAdd(&cur[node], 1);
        csrL[pos] = v & 0x3FFFF;
    }
    __syncthreads();
    for (int j = t; j < n; j += 512)
        csr[cbase + j] = csrL[j];
}

// ---- single-node tail batch (deg>64, rare): groups of 8 edges ----
#define TAIL_GATHER(bN, dN, myEN, myWN, AX, AY, AZ, AW, WS)                         \
    for (int base = 64; base < dN; base += 64) {                                    \
        int mm = dN - base; if (mm > 64) mm = 64;                                   \
        int tE = 0; float tW = 0.f;                                                 \
        if (lane < mm) { tE = csr[bN + base + lane]; tW = dinv[tE]; }               \
        for (int e = 0; e < mm; e += 8) {                                           \
            int   sA = __shfl(tE, e + qe);     float wA = __shfl(tW, e + qe);       \
            int   sB = __shfl(tE, e + 4 + qe); float wB = __shfl(tW, e + 4 + qe);   \
            uint2 vA = *(const uint2*)(tab + sA * NINP + qf * 4);                   \
            uint2 vB = *(const uint2*)(tab + sB * NINP + qf * 4);                   \
            AX += wA * __uint_as_float(vA.x << 16) + wB * __uint_as_float(vB.x << 16);          \
            AY += wA * __uint_as_float(vA.x & 0xffff0000u) + wB * __uint_as_float(vB.x & 0xffff0000u); \
            AZ += wA * __uint_as_float(vA.y << 16) + wB * __uint_as_float(vB.y << 16);          \
            AW += wA * __uint_as_float(vA.y & 0xffff0000u) + wB * __uint_as_float(vB.y & 0xffff0000u); \
            WS += wA + wB;                                                          \
        }                                                                           \
    }

// ---- pair gather: two nodes' quad-row gathers interleaved (4 loads in flight) ----
__device__ __forceinline__ void pair_gather(const ushortT* __restrict__ tab,
                                            const int* __restrict__ csr,
                                            const float* __restrict__ dinv,
                                            int b0, int d0, int b1, int d1,
                                            int lane, int qe, int qf,
                                            int myE0, float myW0, int myE1, float myW1,
                                            float4* g0, float4* g1,
                                            float* sw0, float* sw1) {
    float x0 = 0.f, y0 = 0.f, z0 = 0.f, w0a = 0.f, ws0 = 0.f;
    float x1 = 0.f, y1 = 0.f, z1 = 0.f, w1a = 0.f, ws1 = 0.f;
    int m0 = d0 > 64 ? 64 : d0;
    int m1 = d1 > 64 ? 64 : d1;
    int mx = m0 > m1 ? m0 : m1;
    for (int e = 0; e < mx; e += 8) {
        int   sA0 = __shfl(myE0, e + qe);     float wA0 = __shfl(myW0, e + qe);
        int   sB0 = __shfl(myE0, e + 4 + qe); float wB0 = __shfl(myW0, e + 4 + qe);
        int   sA1 = __shfl(myE1, e + qe);     float wA1 = __shfl(myW1, e + qe);
        int   sB1 = __shfl(myE1, e + 4 + qe); float wB1 = __shfl(myW1, e + 4 + qe);
        uint2 vA0 = *(const uint2*)(tab + sA0 * NINP + qf * 4);
        uint2 vB0 = *(const uint2*)(tab + sB0 * NINP + qf * 4);
        uint2 vA1 = *(const uint2*)(tab + sA1 * NINP + qf * 4);
        uint2 vB1 = *(const uint2*)(tab + sB1 * NINP + qf * 4);
        x0  += wA0 * __uint_as_float(vA0.x << 16)         + wB0 * __uint_as_float(vB0.x << 16);
        y0  += wA0 * __uint_as_float(vA0.x & 0xffff0000u) + wB0 * __uint_as_float(vB0.x & 0xffff0000u);
        z0  += wA0 * __uint_as_float(vA0.y << 16)         + wB0 * __uint_as_float(vB0.y << 16);
        w0a += wA0 * __uint_as_float(vA0.y & 0xffff0000u) + wB0 * __uint_as_float(vB0.y & 0xffff0000u);
        ws0 += wA0 + wB0;
        x1  += wA1 * __uint_as_float(vA1.x << 16)         + wB1 * __uint_as_float(vB1.x << 16);
        y1  += wA1 * __uint_as_float(vA1.x & 0xffff0000u) + wB1 * __uint_as_float(vB1.x & 0xffff0000u);
        z1  += wA1 * __uint_as_float(vA1.y << 16)         + wB1 * __uint_as_float(vB1.y << 16);
        w1a += wA1 * __uint_as_float(vA1.y & 0xffff0000u) + wB1 * __uint_as_float(vB1.y & 0xffff0000u);
        ws1 += wA1 + wB1;
    }
    if (d0 > 64) { TAIL_GATHER(b0, d0, myE0, myW0, x0, y0, z0, w0a, ws0) }
    if (d1 > 64) { TAIL_GATHER(b1, d1, myE1, myW1, x1, y1, z1, w1a, ws1) }
    x0  += __shfl_xor(x0, 16);  x0  += __shfl_xor(x0, 32);
    y0  += __shfl_xor(y0, 16);  y0  += __shfl_xor(y0, 32);
    z0  += __shfl_xor(z0, 16);  z0  += __shfl_xor(z0, 32);
    w0a += __shfl_xor(w0a, 16); w0a += __shfl_xor(w0a, 32);
    ws0 += __shfl_xor(ws0, 16); ws0 += __shfl_xor(ws0, 32);
    x1  += __shfl_xor(x1, 16);  x1  += __shfl_xor(x1, 32);
    y1  += __shfl_xor(y1, 16);  y1  += __shfl_xor(y1, 32);
    z1  += __shfl_xor(z1, 16);  z1  += __shfl_xor(z1, 32);
    w1a += __shfl_xor(w1a, 16); w1a += __shfl_xor(w1a, 32);
    ws1 += __shfl_xor(ws1, 16); ws1 += __shfl_xor(ws1, 32);
    *g0 = make_float4(x0, y0, z0, w0a);
    *g1 = make_float4(x1, y1, z1, w1a);
    *sw0 = ws0; *sw1 = ws1;
}

// ---- K4: layer-1 gather, two nodes per wave iteration, interleaved pair gather ----
__global__ void k_gather1(const int* __restrict__ nlist, const int* __restrict__ ncnt,
                          const int2* __restrict__ rows, const int* __restrict__ csr,
                          const float* __restrict__ dinv, const ushortT* __restrict__ embH,
                          ushortT* __restrict__ P1H) {
    int lane = threadIdx.x & 63;
    int qe = lane >> 4, qf = lane & 15;
    int wid = blockIdx.x * (blockDim.x >> 6) + (threadIdx.x >> 6);
    int nw  = gridDim.x * (blockDim.x >> 6);
    int ncount = *ncnt;
    for (int p = wid; 2 * p < ncount; p += nw) {
        int i0 = nlist[2 * p];
        bool has1 = (2 * p + 1 < ncount);
        int i1 = has1 ? nlist[2 * p + 1] : i0;
        int2 r0 = rows[i0];
        int2 r1 = rows[i1];
        int b0 = r0.x, d0 = r0.y - r0.x;
        int b1 = r1.x, d1 = has1 ? (r1.y - r1.x) : 0;
        float di0 = rsqrtf((float)(d0 + 1));        // == dinv[i0], recomputed
        float di1 = rsqrtf((float)(d1 + 1));
        int m0 = d0 > 64 ? 64 : d0;
        int m1 = d1 > 64 ? 64 : d1;
        int e0 = 0; float w0 = 0.f;
        if (lane < m0) { e0 = csr[b0 + lane]; w0 = dinv[e0]; }
        int e1 = 0; float w1 = 0.f;
        if (lane < m1) { e1 = csr[b1 + lane]; w1 = dinv[e1]; }
        float4 g0, g1; float sw0, sw1;
        pair_gather(embH, csr, dinv, b0, d0, b1, d1, lane, qe, qf,
                    e0, w0, e1, w1, &g0, &g1, &sw0, &sw1);
        if (qe == 0) {
            uint2 sv0 = *(const uint2*)(embH + i0 * NINP + qf * 4);
            ushort4 o0;
            o0.x = f2b(di0 * (di0 * __uint_as_float(sv0.x << 16)         + g0.x));
            o0.y = f2b(di0 * (di0 * __uint_as_float(sv0.x & 0xffff0000u) + g0.y));
            o0.z = f2b(di0 * (di0 * __uint_as_float(sv0.y << 16)         + g0.z));
            o0.w = f2b(di0 * (di0 * __uint_as_float(sv0.y & 0xffff0000u) + g0.w));
            *(ushort4*)(P1H + i0 * NINP + qf * 4) = o0;
            if (has1) {
                uint2 sv1 = *(const uint2*)(embH + i1 * NINP + qf * 4);
                ushort4 o1;
                o1.x = f2b(di1 * (di1 * __uint_as_float(sv1.x << 16)         + g1.x));
                o1.y = f2b(di1 * (di1 * __uint_as_float(sv1.x & 0xffff0000u) + g1.y));
                o1.z = f2b(di1 * (di1 * __uint_as_float(sv1.y << 16)         + g1.z));
                o1.w = f2b(di1 * (di1 * __uint_as_float(sv1.y & 0xffff0000u) + g1.w));
                *(ushort4*)(P1H + i1 * NINP + qf * 4) = o1;
            }
        }
    }
}

// ---- K5: final layer-2 gather (pairing two tokens per wave) + 64x64 GEMM + biases ----
__global__ void k_final(const int* __restrict__ inp, const int2* __restrict__ rows,
                        const int* __restrict__ csr, const float* __restrict__ dinv,
                        const ushortT* __restrict__ P1H, const float* __restrict__ W12,
                        const float* __restrict__ bb, const float* __restrict__ b2,
                        float* __restrict__ out) {
    int t0 = (blockIdx.x * 4 + (threadIdx.x >> 6)) * 2;
    if (t0 >= NBL) return;
    int lane = threadIdx.x & 63;
    int qe = lane >> 4, qf = lane & 15;
    int n0 = inp[t0];
    int n1 = inp[t0 + 1];                   // NBL even -> always valid
    int2 r0 = rows[n0];
    int2 r1 = rows[n1];
    int b0 = r0.x, d0 = r0.y - r0.x;
    int b1 = r1.x, d1 = r1.y - r1.x;
    float dn0 = rsqrtf((float)(d0 + 1));
    float dn1 = rsqrtf((float)(d1 + 1));
    int m0 = d0 > 64 ? 64 : d0;
    int m1 = d1 > 64 ? 64 : d1;
    int e0 = 0; float w0 = 0.f;
    if (lane < m0) { e0 = csr[b0 + lane]; w0 = dinv[e0]; }
    int e1 = 0; float w1 = 0.f;
    if (lane < m1) { e1 = csr[b1 + lane]; w1 = dinv[e1]; }
    float4 g0, g1; float sw0, sw1;
    pair_gather(P1H, csr, dinv, b0, d0, b1, d1, lane, qe, qf,
                e0, w0, e1, w1, &g0, &g1, &sw0, &sw1);
    uint2 sv0 = *(const uint2*)(P1H + n0 * NINP + qf * 4);
    uint2 sv1 = *(const uint2*)(P1H + n1 * NINP + qf * 4);
    float4 p0, p1;
    p0.x = dn0 * (dn0 * __uint_as_float(sv0.x << 16)         + g0.x);
    p0.y = dn0 * (dn0 * __uint_as_float(sv0.x & 0xffff0000u) + g0.y);
    p0.z = dn0 * (dn0 * __uint_as_float(sv0.y << 16)         + g0.z);
    p0.w = dn0 * (dn0 * __uint_as_float(sv0.y & 0xffff0000u) + g0.w);
    p1.x = dn1 * (dn1 * __uint_as_float(sv1.x << 16)         + g1.x);
    p1.y = dn1 * (dn1 * __uint_as_float(sv1.x & 0xffff0000u) + g1.y);
    p1.z = dn1 * (dn1 * __uint_as_float(sv1.y << 16)         + g1.z);
    p1.w = dn1 * (dn1 * __uint_as_float(sv1.y & 0xffff0000u) + g1.w);
    float sS0 = dn0 + sw0;
    float sS1 = dn1 + sw1;
    float bbl = bb[lane], b2l = b2[lane];
    float acc0 = b2l + dn0 * sS0 * bbl;
    float acc1 = b2l + dn1 * sS1 * bbl;
#pragma unroll
    for (int q = 0; q < 16; ++q) {
        float w0c = W12[(4 * q + 0) * 64 + lane];
        float w1c = W12[(4 * q + 1) * 64 + lane];
        float w2c = W12[(4 * q + 2) * 64 + lane];
        float w3c = W12[(4 * q + 3) * 64 + lane];
        acc0 += __shfl(p0.x, q) * w0c + __shfl(p0.y, q) * w1c
              + __shfl(p0.z, q) * w2c + __shfl(p0.w, q) * w3c;
        acc1 += __shfl(p1.x, q) * w0c + __shfl(p1.y, q) * w1c
              + __shfl(p1.z, q) * w2c + __shfl(p1.w, q) * w3c;
    }
    out[t0 * 64 + lane] = acc0;
    out[(t0 + 1) * 64 + lane] = acc1;
}

extern "C" void kernel_launch(void* const* d_in, const int* in_sizes, int n_in,
                              void* d_out, int out_size, void* d_ws, size_t ws_size,
                              hipStream_t stream) {
    const int*   inp  = (const int*)d_in[0];
    const int*   eidx = (const int*)d_in[3];
    const int*   esrc = eidx;
    const int*   edst = eidx + NEDGE;
    const float* emb  = (const float*)d_in[4];
    const float* W1   = (const float*)d_in[5];
    const float* b1   = (const float*)d_in[6];
    const float* W2   = (const float*)d_in[7];
    const float* b2   = (const float*)d_in[8];
    float* out = (float*)d_out;

    char* ws = (char*)d_ws;
    int*           ncnt   = (int*)(ws + 0);            //         4
    unsigned char* mark   = (unsigned char*)(ws + 4096);      // 200,000
    unsigned char* need2  = (unsigned char*)(ws + 204096);    // 200,000
    int2*          rows   = (int2*)(ws + 404096);      //  1,600,000
    float*         dinv   = (float*)(ws + 2004096);    //    800,000
    int*           nlist  = (int*)(ws + 2804096);      //    800,000
    int*           csr    = (int*)(ws + 3604096);      // 12,582,912
    float*         W12    = (float*)(ws + 16187008);   //     16,384
    float*         bb     = (float*)(ws + 16203392);   //        256
    ushortT*       embH   = (ushortT*)(ws + 16203648); // 25,600,000
    ushortT*       P1H    = (ushortT*)(ws + 41803648); // 25,600,000 (end 67,403,648)
    // E + loffT alias the P1H region: both dead before P1H is first written
    int*           E      = (int*)(ws + 41803648);     //  8,011,776
    int*           loffT  = (int*)(ws + 49815424);     //  1,003,428

    const int B = 256;

    k_zero    <<<(404096 / 4 + B - 1) / B, B, 0, stream>>>((int*)ws);
    k_mark_w12<<<67, B, 0, stream>>>(inp, mark, need2, W1, W2, b1, W12, bb);
    k_bucket  <<<NCHK + NCONV, 512, 0, stream>>>(esrc, edst, E, loffT, mark, need2, emb, embH);
    k_csr     <<<NBKT, 512, 0, stream>>>(E, loffT, need2, csr, dinv, rows, nlist, ncnt);

    k_gather1 <<<2048, B, 0, stream>>>(nlist, ncnt, rows, csr, dinv, embH, P1H);
    k_final   <<<(NBL / 2 + 3) / 4, B, 0, stream>>>(inp, rows, csr, dinv, P1H, W12, bb, b2, out);
}